// Round 2
// baseline (289.904 us; speedup 1.0000x reference)
//
#include <hip/hip_runtime.h>
#include <stdint.h>

// Problem constants
#define BB   256
#define NN   2048
#define MM   64
#define CC   512
#define OUTD 198

// Workspace layout (floats)
#define PSTRIDE   256                       // per-batch param block
#define K_OFF     0                         // k[64]
#define E_OFF     64                        // e[64] (post-sigmoid)
#define A_OFF     128                       // a[64]
#define BETA_OFF  192
#define G_OFF     193
#define GAMMA_OFF 194
#define S_OFF     195                       // s[3]
#define KNORM_OFF 198
#define LOGITS_OFF (BB * PSTRIDE)           // [B,N] fp32 logits
#define WF_OFF     (LOGITS_OFF + BB * NN)   // [B,N] fp32 final w

__device__ __forceinline__ float softplusf(float x) {
    return x > 20.f ? x : log1pf(expf(x));
}
__device__ __forceinline__ float sigmoidf(float x) {
    return 1.f / (1.f + expf(-x));
}

// ---------------------------------------------------------------------------
// Kernel 1: controller projection o = h @ W^T + b, split + activations.
// One block per batch, 256 threads. W (405 KB) is L2/LLC-cached across blocks.
// ---------------------------------------------------------------------------
__global__ __launch_bounds__(256) void k_ctrl(
        const float* __restrict__ h, const float* __restrict__ Wm,
        const float* __restrict__ bias, float* __restrict__ ws) {
    __shared__ float hs[CC];
    __shared__ float os[OUTD];
    const int b = blockIdx.x, t = threadIdx.x;

    for (int c = t; c < CC; c += 256) hs[c] = h[b * CC + c];
    __syncthreads();

    if (t < OUTD) {
        const float* wr = Wm + (size_t)t * CC;
        float acc = 0.f;
        #pragma unroll 8
        for (int c = 0; c < CC; c += 4) {
            float4 p = *(const float4*)(wr + c);
            acc += p.x * hs[c+0] + p.y * hs[c+1] + p.z * hs[c+2] + p.w * hs[c+3];
        }
        os[t] = acc + bias[t];
    }
    __syncthreads();

    float* P = ws + (size_t)b * PSTRIDE;
    if (t < 64) {
        P[K_OFF + t] = os[t];
    } else if (t == 64) {
        P[BETA_OFF] = softplusf(os[64]);
    } else if (t == 65) {
        P[G_OFF] = sigmoidf(os[65]);
    } else if (t == 66) {   // 3-way softmax for shift weights
        float x0 = os[66], x1 = os[67], x2 = os[68];
        float mx = fmaxf(x0, fmaxf(x1, x2));
        float e0 = expf(x0 - mx), e1 = expf(x1 - mx), e2 = expf(x2 - mx);
        float inv = 1.f / (e0 + e1 + e2);
        P[S_OFF + 0] = e0 * inv; P[S_OFF + 1] = e1 * inv; P[S_OFF + 2] = e2 * inv;
    } else if (t == 69) {
        P[GAMMA_OFF] = 1.f + softplusf(os[69]);
    } else if (t >= 70 && t < 134) {
        P[E_OFF + (t - 70)] = sigmoidf(os[t]);
    } else if (t >= 134 && t < 198) {
        P[A_OFF + (t - 134)] = os[t];
    } else if (t == 198) {  // ||k + 1e-16||
        float ss = 0.f;
        for (int i = 0; i < MM; ++i) { float kv = os[i] + 1e-16f; ss += kv * kv; }
        P[KNORM_OFF] = sqrtf(ss);
    }
}

// ---------------------------------------------------------------------------
// Kernel 2: content-addressing logits = beta * sim / max(|mem_e|*|k_e|, 1e-8).
// 8 blocks per batch, 256 rows each. 16 lanes/row x float4 (16B) loads ->
// 4KB coalesced per block-iteration; xor-shuffle reduce dot & sum-of-squares.
// ---------------------------------------------------------------------------
__global__ __launch_bounds__(256) void k_logits(
        const float* __restrict__ mem, float* __restrict__ ws) {
    const int b = blockIdx.x >> 3;
    const int chunk = blockIdx.x & 7;
    const int t = threadIdx.x;
    const int l = t & 15;       // lane within 16-group
    const int grp = t >> 4;     // 16 groups/block

    const float* P = ws + (size_t)b * PSTRIDE;
    float kv[4];
    #pragma unroll
    for (int i = 0; i < 4; ++i) kv[i] = P[K_OFF + 4 * l + i] + 1e-16f;
    const float beta  = P[BETA_OFF];
    const float knorm = P[KNORM_OFF];
    float* lg = ws + LOGITS_OFF + (size_t)b * NN;

    const int row0 = chunk * 256;
    #pragma unroll
    for (int it = 0; it < 16; ++it) {
        const int row = row0 + it * 16 + grp;
        float4 p = *(const float4*)(mem + ((size_t)b * NN + row) * MM + 4 * l);
        float m0 = p.x + 1e-16f, m1 = p.y + 1e-16f, m2 = p.z + 1e-16f, m3 = p.w + 1e-16f;
        float dot = m0 * kv[0] + m1 * kv[1] + m2 * kv[2] + m3 * kv[3];
        float ss  = m0 * m0 + m1 * m1 + m2 * m2 + m3 * m3;
        #pragma unroll
        for (int off = 1; off < 16; off <<= 1) {
            dot += __shfl_xor(dot, off, 64);
            ss  += __shfl_xor(ss,  off, 64);
        }
        if (l == 0) {
            float denom = fmaxf(sqrtf(ss) * knorm, 1e-8f);
            lg[row] = beta * dot / denom;
        }
    }
}

// Block reductions (4 waves of 64)
__device__ __forceinline__ float bred_max(float v, float* red) {
    #pragma unroll
    for (int off = 32; off; off >>= 1) v = fmaxf(v, __shfl_down(v, off, 64));
    if ((threadIdx.x & 63) == 0) red[threadIdx.x >> 6] = v;
    __syncthreads();
    float r = fmaxf(fmaxf(red[0], red[1]), fmaxf(red[2], red[3]));
    __syncthreads();
    return r;
}
__device__ __forceinline__ float bred_sum(float v, float* red) {
    #pragma unroll
    for (int off = 32; off; off >>= 1) v += __shfl_down(v, off, 64);
    if ((threadIdx.x & 63) == 0) red[threadIdx.x >> 6] = v;
    __syncthreads();
    float r = red[0] + red[1] + red[2] + red[3];
    __syncthreads();
    return r;
}

// ---------------------------------------------------------------------------
// Kernel 3: softmax -> gate -> circular shift -> sharpen -> normalize.
// One block per batch, N=2048 elems, 8 per thread, all in LDS.
// ---------------------------------------------------------------------------
__global__ __launch_bounds__(256) void k_addr(
        const float* __restrict__ w_prev, float* __restrict__ ws,
        float* __restrict__ w_out) {
    __shared__ float buf[NN];    // w_g
    __shared__ float buf2[NN];   // w_s
    __shared__ float red[4];
    const int b = blockIdx.x, t = threadIdx.x;
    const float* P  = ws + (size_t)b * PSTRIDE;
    const float* lg = ws + LOGITS_OFF + (size_t)b * NN;

    const float g  = P[G_OFF];
    const float s0 = P[S_OFF + 0], s1 = P[S_OFF + 1], s2 = P[S_OFF + 2];
    const float gamma = P[GAMMA_OFF];

    float v[8];
    float lmax = -1e30f;
    #pragma unroll
    for (int i = 0; i < 8; ++i) { v[i] = lg[t + i * 256]; lmax = fmaxf(lmax, v[i]); }
    lmax = bred_max(lmax, red);

    float lsum = 0.f;
    #pragma unroll
    for (int i = 0; i < 8; ++i) { v[i] = expf(v[i] - lmax); lsum += v[i]; }
    lsum = bred_sum(lsum, red);
    const float inv = 1.f / lsum;

    #pragma unroll
    for (int i = 0; i < 8; ++i) {
        const int n = t + i * 256;
        float wc = v[i] * inv;
        buf[n] = g * wc + (1.f - g) * w_prev[(size_t)b * NN + n];
    }
    __syncthreads();

    float psum = 0.f;
    #pragma unroll
    for (int i = 0; i < 8; ++i) {
        const int n = t + i * 256;
        float wt = buf[(n + NN - 1) & (NN - 1)] * s0 + buf[n] * s1
                 + buf[(n + 1) & (NN - 1)] * s2;
        float wsv = (wt > 0.f) ? exp2f(gamma * log2f(wt)) : 0.f;
        buf2[n] = wsv;
        psum += wsv;
    }
    psum = bred_sum(psum, red);
    const float invp = 1.f / (psum + 1e-16f);

    float* wf = ws + WF_OFF + (size_t)b * NN;
    #pragma unroll
    for (int i = 0; i < 8; ++i) {
        const int n = t + i * 256;
        float wv = buf2[n] * invp;
        wf[n] = wv;
        w_out[(size_t)b * NN + n] = wv;
    }
}

// ---------------------------------------------------------------------------
// Kernel 4: mem_new = memory * (1 - w*e) + w*a.  float4 (16B) per thread-rep,
// fully coalesced; e/a/w hit L1/L2 (tiny, heavily reused).
// ---------------------------------------------------------------------------
__global__ __launch_bounds__(256) void k_write(
        const float* __restrict__ mem, const float* __restrict__ ws,
        float* __restrict__ out_mem) {
    const float* wf = ws + WF_OFF;
    const size_t tid0 = (size_t)blockIdx.x * 256 + threadIdx.x;
    #pragma unroll
    for (int rep = 0; rep < 4; ++rep) {
        const size_t u = tid0 + (size_t)rep * (8192u * 256u);
        const size_t base = u * 4;                 // element index
        const int b = (int)(base >> 17);           // / (N*M)
        const int n = (int)(base >> 6) & (NN - 1);
        const int m = (int)base & (MM - 1);

        const float w = wf[((size_t)b << 11) + n];
        const float* P = ws + (size_t)b * PSTRIDE;
        float4 p = *(const float4*)(mem + base);

        float4 o;
        o.x = p.x * (1.f - w * P[E_OFF + m + 0]) + w * P[A_OFF + m + 0];
        o.y = p.y * (1.f - w * P[E_OFF + m + 1]) + w * P[A_OFF + m + 1];
        o.z = p.z * (1.f - w * P[E_OFF + m + 2]) + w * P[A_OFF + m + 2];
        o.w = p.w * (1.f - w * P[E_OFF + m + 3]) + w * P[A_OFF + m + 3];
        *(float4*)(out_mem + base) = o;
    }
}

extern "C" void kernel_launch(void* const* d_in, const int* in_sizes, int n_in,
                              void* d_out, int out_size, void* d_ws, size_t ws_size,
                              hipStream_t stream) {
    const float* h      = (const float*)d_in[0];
    const float* w_prev = (const float*)d_in[1];
    const float* memory = (const float*)d_in[2];
    const float* W      = (const float*)d_in[3];
    const float* bias   = (const float*)d_in[4];
    float* out = (float*)d_out;
    float* ws = (float*)d_ws;

    k_ctrl  <<<BB,     256, 0, stream>>>(h, W, bias, ws);
    k_logits<<<BB * 8, 256, 0, stream>>>(memory, ws);
    k_addr  <<<BB,     256, 0, stream>>>(w_prev, ws, out);
    k_write <<<8192,   256, 0, stream>>>(memory, ws, out + (size_t)BB * NN);
}

// Round 4
// 286.719 us; speedup vs baseline: 1.0111x; 1.0111x over previous
//
#include <hip/hip_runtime.h>
#include <stdint.h>

// Problem constants
#define BB   256
#define NN   2048
#define MM   64
#define CC   512
#define OUTD 198

// Workspace layout (floats)
#define PSTRIDE   256                       // per-batch param block
#define K_OFF     0                         // k[64]
#define E_OFF     64                        // e[64] (post-sigmoid)
#define A_OFF     128                       // a[64]
#define BETA_OFF  192
#define G_OFF     193
#define GAMMA_OFF 194
#define S_OFF     195                       // s[3]
#define KNORM_OFF 198
#define LOGITS_OFF (BB * PSTRIDE)           // [B,N] fp32 logits

typedef float vf4 __attribute__((ext_vector_type(4)));  // clang-native, valid for nontemporal builtins

__device__ __forceinline__ float softplusf(float x) {
    return x > 20.f ? x : log1pf(expf(x));
}
__device__ __forceinline__ float sigmoidf(float x) {
    return 1.f / (1.f + expf(-x));
}

// ---------------------------------------------------------------------------
// Kernel 1: controller projection o = h @ W^T + b, split + activations.
// One block per batch, 256 threads. W (405 KB) is L2/LLC-cached across blocks.
// ---------------------------------------------------------------------------
__global__ __launch_bounds__(256) void k_ctrl(
        const float* __restrict__ h, const float* __restrict__ Wm,
        const float* __restrict__ bias, float* __restrict__ ws) {
    __shared__ float hs[CC];
    __shared__ float os[OUTD];
    const int b = blockIdx.x, t = threadIdx.x;

    for (int c = t; c < CC; c += 256) hs[c] = h[b * CC + c];
    __syncthreads();

    if (t < OUTD) {
        const float* wr = Wm + (size_t)t * CC;
        float acc = 0.f;
        #pragma unroll 8
        for (int c = 0; c < CC; c += 4) {
            float4 p = *(const float4*)(wr + c);
            acc += p.x * hs[c+0] + p.y * hs[c+1] + p.z * hs[c+2] + p.w * hs[c+3];
        }
        os[t] = acc + bias[t];
    }
    __syncthreads();

    float* P = ws + (size_t)b * PSTRIDE;
    if (t < 64) {
        P[K_OFF + t] = os[t];
    } else if (t == 64) {
        P[BETA_OFF] = softplusf(os[64]);
    } else if (t == 65) {
        P[G_OFF] = sigmoidf(os[65]);
    } else if (t == 66) {   // 3-way softmax for shift weights
        float x0 = os[66], x1 = os[67], x2 = os[68];
        float mx = fmaxf(x0, fmaxf(x1, x2));
        float e0 = expf(x0 - mx), e1 = expf(x1 - mx), e2 = expf(x2 - mx);
        float inv = 1.f / (e0 + e1 + e2);
        P[S_OFF + 0] = e0 * inv; P[S_OFF + 1] = e1 * inv; P[S_OFF + 2] = e2 * inv;
    } else if (t == 69) {
        P[GAMMA_OFF] = 1.f + softplusf(os[69]);
    } else if (t >= 70 && t < 134) {
        P[E_OFF + (t - 70)] = sigmoidf(os[t]);
    } else if (t >= 134 && t < 198) {
        P[A_OFF + (t - 134)] = os[t];
    } else if (t == 198) {  // ||k + 1e-16||
        float ss = 0.f;
        for (int i = 0; i < MM; ++i) { float kv = os[i] + 1e-16f; ss += kv * kv; }
        P[KNORM_OFF] = sqrtf(ss);
    }
}

// ---------------------------------------------------------------------------
// Kernel 2: content-addressing logits = beta * sim / max(|mem_e|*|k_e|, 1e-8).
// 8 blocks per batch, 256 rows each. 16 lanes/row x float4 (16B) loads ->
// 4KB coalesced per block-iteration; xor-shuffle reduce dot & sum-of-squares.
// Normal (caching) loads on purpose: pulls `memory` into LLC for k_write.
// ---------------------------------------------------------------------------
__global__ __launch_bounds__(256) void k_logits(
        const float* __restrict__ mem, float* __restrict__ ws) {
    const int b = blockIdx.x >> 3;
    const int chunk = blockIdx.x & 7;
    const int t = threadIdx.x;
    const int l = t & 15;       // lane within 16-group
    const int grp = t >> 4;     // 16 groups/block

    const float* P = ws + (size_t)b * PSTRIDE;
    float kv[4];
    #pragma unroll
    for (int i = 0; i < 4; ++i) kv[i] = P[K_OFF + 4 * l + i] + 1e-16f;
    const float beta  = P[BETA_OFF];
    const float knorm = P[KNORM_OFF];
    float* lg = ws + LOGITS_OFF + (size_t)b * NN;

    const int row0 = chunk * 256;
    #pragma unroll
    for (int it = 0; it < 16; ++it) {
        const int row = row0 + it * 16 + grp;
        float4 p = *(const float4*)(mem + ((size_t)b * NN + row) * MM + 4 * l);
        float m0 = p.x + 1e-16f, m1 = p.y + 1e-16f, m2 = p.z + 1e-16f, m3 = p.w + 1e-16f;
        float dot = m0 * kv[0] + m1 * kv[1] + m2 * kv[2] + m3 * kv[3];
        float ss  = m0 * m0 + m1 * m1 + m2 * m2 + m3 * m3;
        #pragma unroll
        for (int off = 1; off < 16; off <<= 1) {
            dot += __shfl_xor(dot, off, 64);
            ss  += __shfl_xor(ss,  off, 64);
        }
        if (l == 0) {
            float denom = fmaxf(sqrtf(ss) * knorm, 1e-8f);
            lg[row] = beta * dot / denom;
        }
    }
}

// Block reductions (4 waves of 64)
__device__ __forceinline__ float bred_max(float v, float* red) {
    #pragma unroll
    for (int off = 32; off; off >>= 1) v = fmaxf(v, __shfl_down(v, off, 64));
    if ((threadIdx.x & 63) == 0) red[threadIdx.x >> 6] = v;
    __syncthreads();
    float r = fmaxf(fmaxf(red[0], red[1]), fmaxf(red[2], red[3]));
    __syncthreads();
    return r;
}
__device__ __forceinline__ float bred_sum(float v, float* red) {
    #pragma unroll
    for (int off = 32; off; off >>= 1) v += __shfl_down(v, off, 64);
    if ((threadIdx.x & 63) == 0) red[threadIdx.x >> 6] = v;
    __syncthreads();
    float r = red[0] + red[1] + red[2] + red[3];
    __syncthreads();
    return r;
}

// ---------------------------------------------------------------------------
// Kernel 3: softmax -> gate -> circular shift -> sharpen -> normalize.
// One block per batch, N=2048 elems, 8 per thread, all in LDS.
// Writes final w ONLY to d_out; k_write reads it back from there.
// ---------------------------------------------------------------------------
__global__ __launch_bounds__(256) void k_addr(
        const float* __restrict__ w_prev, float* __restrict__ ws,
        float* __restrict__ w_out) {
    __shared__ float buf[NN];    // w_g
    __shared__ float buf2[NN];   // w_s
    __shared__ float red[4];
    const int b = blockIdx.x, t = threadIdx.x;
    const float* P  = ws + (size_t)b * PSTRIDE;
    const float* lg = ws + LOGITS_OFF + (size_t)b * NN;

    const float g  = P[G_OFF];
    const float s0 = P[S_OFF + 0], s1 = P[S_OFF + 1], s2 = P[S_OFF + 2];
    const float gamma = P[GAMMA_OFF];

    float v[8];
    float lmax = -1e30f;
    #pragma unroll
    for (int i = 0; i < 8; ++i) { v[i] = lg[t + i * 256]; lmax = fmaxf(lmax, v[i]); }
    lmax = bred_max(lmax, red);

    float lsum = 0.f;
    #pragma unroll
    for (int i = 0; i < 8; ++i) { v[i] = expf(v[i] - lmax); lsum += v[i]; }
    lsum = bred_sum(lsum, red);
    const float inv = 1.f / lsum;

    #pragma unroll
    for (int i = 0; i < 8; ++i) {
        const int n = t + i * 256;
        float wc = v[i] * inv;
        buf[n] = g * wc + (1.f - g) * w_prev[(size_t)b * NN + n];
    }
    __syncthreads();

    float psum = 0.f;
    #pragma unroll
    for (int i = 0; i < 8; ++i) {
        const int n = t + i * 256;
        float wt = buf[(n + NN - 1) & (NN - 1)] * s0 + buf[n] * s1
                 + buf[(n + 1) & (NN - 1)] * s2;
        float wsv = (wt > 0.f) ? exp2f(gamma * log2f(wt)) : 0.f;
        buf2[n] = wsv;
        psum += wsv;
    }
    psum = bred_sum(psum, red);
    const float invp = 1.f / (psum + 1e-16f);

    #pragma unroll
    for (int i = 0; i < 8; ++i) {
        const int n = t + i * 256;
        w_out[(size_t)b * NN + n] = buf2[n] * invp;
    }
}

// ---------------------------------------------------------------------------
// Kernel 4: mem_new = memory * (1 - w*e) + w*a.  float4 (16B) per thread-rep,
// fully coalesced. NONTEMPORAL stores for mem_new: keeps the output stream
// from write-allocating in the Infinity Cache, so the `memory` re-read (just
// cached by k_logits, 134 MB < 256 MiB LLC) stays an LLC hit instead of
// being evicted back to HBM mid-kernel.
// ---------------------------------------------------------------------------
__global__ __launch_bounds__(256) void k_write(
        const float* __restrict__ mem, const float* __restrict__ ws,
        const float* __restrict__ w_in, float* __restrict__ out_mem) {
    const size_t tid0 = (size_t)blockIdx.x * 256 + threadIdx.x;
    #pragma unroll
    for (int rep = 0; rep < 8; ++rep) {
        const size_t u = tid0 + (size_t)rep * (4096u * 256u);
        const size_t base = u * 4;                 // element index
        const int b = (int)(base >> 17);           // / (N*M)
        const int n = (int)(base >> 6) & (NN - 1);
        const int m = (int)base & (MM - 1);

        const float w = w_in[((size_t)b << 11) + n];
        const float* P = ws + (size_t)b * PSTRIDE;
        float4 p = *(const float4*)(mem + base);

        vf4 o;
        o.x = p.x * (1.f - w * P[E_OFF + m + 0]) + w * P[A_OFF + m + 0];
        o.y = p.y * (1.f - w * P[E_OFF + m + 1]) + w * P[A_OFF + m + 1];
        o.z = p.z * (1.f - w * P[E_OFF + m + 2]) + w * P[A_OFF + m + 2];
        o.w = p.w * (1.f - w * P[E_OFF + m + 3]) + w * P[A_OFF + m + 3];
        __builtin_nontemporal_store(o, (vf4*)(out_mem + base));
    }
}

extern "C" void kernel_launch(void* const* d_in, const int* in_sizes, int n_in,
                              void* d_out, int out_size, void* d_ws, size_t ws_size,
                              hipStream_t stream) {
    const float* h      = (const float*)d_in[0];
    const float* w_prev = (const float*)d_in[1];
    const float* memory = (const float*)d_in[2];
    const float* W      = (const float*)d_in[3];
    const float* bias   = (const float*)d_in[4];
    float* out = (float*)d_out;
    float* ws = (float*)d_ws;

    float* w_out   = out;                       // [B,N]
    float* mem_out = out + (size_t)BB * NN;     // [B,N,M]

    k_ctrl  <<<BB,     256, 0, stream>>>(h, W, bias, ws);
    k_logits<<<BB * 8, 256, 0, stream>>>(memory, ws);
    k_addr  <<<BB,     256, 0, stream>>>(w_prev, ws, w_out);
    k_write <<<4096,   256, 0, stream>>>(memory, ws, w_out, mem_out);
}